// Round 7
// baseline (871.416 us; speedup 1.0000x reference)
//
#include <hip/hip_runtime.h>

typedef unsigned short u16;
typedef unsigned int u32;

#define BB 8
#define CC 128
#define TT_ 1000
#define TPAD 1024
#define NB 31
#define MAXBW 16
#define MAXOC 128
#define GRID_P 960

typedef __bf16 bf16x8 __attribute__((ext_vector_type(8)));
typedef float f32x4 __attribute__((ext_vector_type(4)));

__device__ __forceinline__ u16 f2bf(float f) {
    u32 u = __float_as_uint(f);
    return (u16)((u + 0x7fffu + ((u >> 16) & 1u)) >> 16);
}
__device__ __forceinline__ float bf2f(u16 h) { return __uint_as_float(((u32)h) << 16); }
__device__ __forceinline__ int bandBW(int i) { return (i < 10) ? 3 : ((i < 22) ? 8 : ((i < 30) ? 16 : 3)); }
__device__ __forceinline__ int bandF0(int i) {
    return (i < 10) ? 3 * i : ((i < 22) ? 30 + 8 * (i - 10) : ((i < 30) ? 126 + 16 * (i - 22) : 254));
}

// ==================== SHARED TASK BODIES ====================

// Transpose task (r4/r6-proven streaming form). tile = 32x500 u16 (32,000B).
// xt slot indexed by GLOBAL b: [b][band][cblk 16][t 1024][8c] bf16.
__device__ __forceinline__ void kstat_task(const float* __restrict__ x,
                                           u16* __restrict__ xt,
                                           float* __restrict__ partials,
                                           u16* tile, int tw, int cg, int b) {
    const int tid = threadIdx.x, lane = tid & 63, w = tid >> 6;
    __syncthreads();                               // LDS handoff from previous task
    const int NF4 = (tw == 62) ? 62 : 124;
    if (tw == 62) {
        u32* t32 = (u32*)tile;
        for (int n = tid; n < 8000; n += 256) t32[n] = 0;
        __syncthreads();
    }

    const f32x4* src4 = (const f32x4*)(x + (size_t)b * (CC * TT_ * NB));
    const int fbase = tw * 124;

    // load phase: 16 float4/thread, pinned live (anti r5-regalloc-collapse)
    f32x4 v[16];
    #pragma unroll
    for (int k = 0; k < 8; ++k) {
        const int c = cg * 32 + w * 8 + k;
        const f32x4* p = src4 + (size_t)c * 7750 + fbase;
        int o0 = lane, o1 = 64 + lane;
        o0 = (o0 < NF4) ? o0 : 0;
        o1 = (o1 < NF4) ? o1 : 0;
        v[2 * k]     = p[o0];
        v[2 * k + 1] = p[o1];
    }
    #pragma unroll
    for (int k = 0; k < 16; ++k) asm volatile("" : "+v"(v[k]));
    __builtin_amdgcn_sched_barrier(0);

    // convert + LDS write: one b64 per float4, lane-linear
    #pragma unroll
    for (int k = 0; k < 8; ++k) {
        u16* row = tile + (w * 8 + k) * 500;
        #pragma unroll
        for (int it = 0; it < 2; ++it) {
            const int off = it * 64 + lane;
            f32x4 vv = v[2 * k + it];
            ushort4 pk;
            pk.x = f2bf(vv.x); pk.y = f2bf(vv.y); pk.z = f2bf(vv.z); pk.w = f2bf(vv.w);
            if (off < NF4) *(ushort4*)(row + 4 * off) = pk;
        }
    }
    __syncthreads();

    // store pass: gather 8 c's per uint4, 256B runs
    uint4* dst4 = (uint4*)xt;
    const int t0 = tw * 16;
    for (int n = tid; n < 1984; n += 256) {
        int task = n >> 4, m = n & 15;
        int band = task >> 2, cbl = task & 3;
        int fidx = m * 31 + band;
        u16 e[8];
        #pragma unroll
        for (int j = 0; j < 8; ++j)
            e[j] = tile[(8 * cbl + j) * 500 + fidx];
        uint4 u;
        u.x = (u32)e[0] | ((u32)e[1] << 16);
        u.y = (u32)e[2] | ((u32)e[3] << 16);
        u.z = (u32)e[4] | ((u32)e[5] << 16);
        u.w = (u32)e[6] | ((u32)e[7] << 16);
        dst4[((size_t)(b * NB + band) * 16 + (cg * 4 + cbl)) * TPAD + t0 + m] = u;
    }

    // stats: 8 lanes/band, shfl reduce
    if (tid < 248) {
        int band = tid >> 3, slot = tid & 7;
        float s = 0.f, sq = 0.f;
        #pragma unroll
        for (int ci = 0; ci < 32; ++ci) {
            #pragma unroll
            for (int d = 0; d < 2; ++d) {
                float f = bf2f(tile[ci * 500 + (2 * slot + d) * 31 + band]);
                s += f; sq += f * f;
            }
        }
        #pragma unroll
        for (int off = 1; off < 8; off <<= 1) {
            s  += __shfl_xor(s, off);
            sq += __shfl_xor(sq, off);
        }
        if (slot == 0) {
            int ch = tw * 4 + cg;
            *(float2*)&partials[((size_t)(b * NB + band) * 256 + ch) * 2] = make_float2(s, sq);
        }
    }
}

// Fold-W task (one band; 256 threads; r5 fold math, numerically verified).
__device__ __forceinline__ void fold_task(const float* __restrict__ convw,
                                          const float* __restrict__ gamma,
                                          const float* __restrict__ beta,
                                          u16* __restrict__ wgT2,
                                          float* __restrict__ wbArr,
                                          float* __restrict__ wgsArr,
                                          float* fs, int band) {
    const int tid = threadIdx.x;
    float* g  = fs;
    float* be = fs + 128;
    __syncthreads();                               // LDS handoff
    if (tid < 128) { g[tid] = gamma[band * CC + tid]; be[tid] = beta[band * CC + tid]; }
    __syncthreads();
    const int oc = bandBW(band) * 8;
    if (tid < 128) {
        float wb = 0.f, wgs = 0.f;
        for (int c = 0; c < CC; ++c) {
            float wv = convw[(size_t)(band * MAXOC + tid) * CC + c];
            wb += wv * be[c];
            wgs += wv * g[c];
        }
        wbArr[band * CC + tid] = wb;
        wgsArr[band * CC + tid] = wgs;
    }
    const int c = tid & 127, oh = tid >> 7;
    const float gc = g[c];
    for (int o = oh * 64; o < oh * 64 + 64; ++o) {
        float wv = convw[(size_t)(band * MAXOC + o) * CC + c];
        wgT2[(size_t)(band * MAXOC + o) * CC + c] = (o < oc) ? f2bf(wv * gc) : (u16)0;
    }
}

// kmm body (r5/r6-verified). xslot = xt batch slot (global b in fused path).
#define YMAXF 4224
template <int ROWS, int WM, int WN, int RF, int CF, int TSTEP, int NSTEPS>
__device__ __forceinline__ void kmm_body(float* __restrict__ Y, float* __restrict__ bo,
                                         float* __restrict__ red,
                                         const u16* __restrict__ xt,
                                         const u16* __restrict__ wgT2,
                                         const float* __restrict__ partials,
                                         const float* __restrict__ wbArr,
                                         const float* __restrict__ wgsArr,
                                         const float* __restrict__ cb,
                                         const float* __restrict__ ctxr,
                                         const float* __restrict__ ctxi,
                                         float* __restrict__ out,
                                         int i, int b, int xslot, int bx, long long outSize) {
    const int tid = threadIdx.x;
    const int w = tid >> 6, l = tid & 63;
    const int wm = w % WM, wn = w / WM;
    const int RB = wm * 16 * RF;
    const int CB = wn * 16 * CF;
    const int lr = l & 15, lk = l >> 4;
    constexpr int PITCH = TSTEP + 1;

    // A fragments first (overlaps reduce latency)
    const uint4* wb4 = (const uint4*)(wgT2 + (size_t)i * MAXOC * CC);
    bf16x8 a[RF][4];
    #pragma unroll
    for (int rf = 0; rf < RF; ++rf)
        #pragma unroll
        for (int ks = 0; ks < 4; ++ks)
            a[rf][ks] = __builtin_bit_cast(bf16x8,
                wb4[((RB + rf * 16 + lr) * CC + lk * 8 + ks * 32) >> 3]);

    // fused stats reduction
    float s = 0.f, sq = 0.f;
    for (int n = tid; n < 252; n += 256) {
        float2 p = *(const float2*)&partials[((size_t)(b * NB + i) * 256 + n) * 2];
        s += p.x; sq += p.y;
    }
    #pragma unroll
    for (int off = 1; off < 64; off <<= 1) {
        s  += __shfl_xor(s, off);
        sq += __shfl_xor(sq, off);
    }
    if ((tid & 63) == 0) {
        red[(tid >> 6) * 2]     = s;
        red[(tid >> 6) * 2 + 1] = sq;
    }
    __syncthreads();
    s  = red[0] + red[2] + red[4] + red[6];
    sq = red[1] + red[3] + red[5] + red[7];
    const float mean = s * (1.f / 128000.f);
    const float var  = sq * (1.f / 128000.f) - mean * mean;
    const float rstd = rsqrtf(var + 1e-8f);
    for (int n = tid; n < ROWS; n += 256)
        bo[n] = cb[i * MAXOC + n] + wbArr[i * CC + n] - mean * rstd * wgsArr[i * CC + n];

    const uint4* xb4 = ((const uint4*)xt) + (size_t)(xslot * NB + i) * 16 * TPAD;
    const int bw = bandBW(i), F0 = bandF0(i);

    for (int st = 0; st < NSTEPS; ++st) {
        const int t0 = (bx * NSTEPS + st) * TSTEP;
        __syncthreads();

        bf16x8 bf[CF][4];
        #pragma unroll
        for (int cf = 0; cf < CF; ++cf)
            #pragma unroll
            for (int ks = 0; ks < 4; ++ks)
                bf[cf][ks] = __builtin_bit_cast(bf16x8,
                    xb4[(size_t)(lk + ks * 4) * TPAD + (t0 + CB + cf * 16 + lr)]);

        f32x4 acc[RF][CF];
        #pragma unroll
        for (int rf = 0; rf < RF; ++rf)
            #pragma unroll
            for (int cf = 0; cf < CF; ++cf)
                acc[rf][cf] = (f32x4){0.f, 0.f, 0.f, 0.f};

        #pragma unroll
        for (int ks = 0; ks < 4; ++ks)
            #pragma unroll
            for (int rf = 0; rf < RF; ++rf)
                #pragma unroll
                for (int cf = 0; cf < CF; ++cf)
                    acc[rf][cf] = __builtin_amdgcn_mfma_f32_16x16x32_bf16(
                        a[rf][ks], bf[cf][ks], acc[rf][cf], 0, 0, 0);

        #pragma unroll
        for (int rf = 0; rf < RF; ++rf)
            #pragma unroll
            for (int cf = 0; cf < CF; ++cf)
                #pragma unroll
                for (int r = 0; r < 4; ++r) {
                    int row = RB + rf * 16 + lk * 4 + r;
                    float vv = rstd * acc[rf][cf][r] + bo[row];
                    Y[row * PITCH + CB + cf * 16 + lr] = fmaxf(vv, 0.f);
                }
        __syncthreads();

        const int jobs = 2 * bw * TSTEP;
        for (int n = tid; n < jobs; n += 256) {
            int tl = n % TSTEP, sf = n / TSTEP;
            int ss = sf / bw, f = sf - ss * bw;
            int t = t0 + tl;
            if (t < TT_) {
                float lrv = Y[(ss * bw + f) * PITCH + tl];
                float liv = Y[(2 * bw + ss * bw + f) * PITCH + tl];
                float grv = Y[(4 * bw + ss * bw + f) * PITCH + tl];
                float giv = Y[(6 * bw + ss * bw + f) * PITCH + tl];
                float mr = lrv * (1.f / (1.f + __expf(-grv)));
                float mi = liv * (1.f / (1.f + __expf(-giv)));
                size_t cidx = ((size_t)(i * BB + b) * MAXBW + f) * TT_ + t;
                float cr = ctxr[cidx], ci = ctxi[cidx];
                long long ridx = ((long long)((b * 2 + ss) * 257 + F0 + f)) * TT_ + t;
                if (ridx < outSize) out[ridx] = cr * mr - ci * mi;
            }
        }
    }
}

__device__ __forceinline__ void mm_task(float* fs,
                                        const u16* __restrict__ xt,
                                        const u16* __restrict__ wgT2,
                                        const float* __restrict__ partials,
                                        const float* __restrict__ wbArr,
                                        const float* __restrict__ wgsArr,
                                        const float* __restrict__ cb,
                                        const float* __restrict__ ctxr,
                                        const float* __restrict__ ctxi,
                                        float* __restrict__ out,
                                        int i, int bx, int b, long long outSize) {
    float* Y   = fs;
    float* bo  = fs + YMAXF;
    float* red = bo + 128;
    __syncthreads();                               // LDS handoff (red/bo overlap tile)
    if (i < 10 || i == 30)
        kmm_body<32, 2, 2, 1, 4, 128, 1>(Y, bo, red, xt, wgT2, partials, wbArr, wgsArr, cb, ctxr, ctxi, out, i, b, b, bx, outSize);
    else if (i < 22)
        kmm_body<64, 4, 1, 1, 4, 64, 2>(Y, bo, red, xt, wgT2, partials, wbArr, wgsArr, cb, ctxr, ctxi, out, i, b, b, bx, outSize);
    else
        kmm_body<128, 4, 1, 2, 2, 32, 4>(Y, bo, red, xt, wgT2, partials, wbArr, wgsArr, cb, ctxr, ctxi, out, i, b, b, bx, outSize);
}

// ==================== FUSED PERSISTENT KERNEL ====================

// Grid barrier: all GRID_P blocks are co-resident by construction
// (launch_bounds(256,4) => 4 blocks/CU, 32,000B LDS => 128KB/CU <= 160KB).
__device__ __forceinline__ void gbar(int* bar, int target) {
    __syncthreads();
    if (threadIdx.x == 0) {
        __threadfence();
        __hip_atomic_fetch_add(bar, 1, __ATOMIC_ACQ_REL, __HIP_MEMORY_SCOPE_AGENT);
        while (__hip_atomic_load(bar, __ATOMIC_ACQUIRE, __HIP_MEMORY_SCOPE_AGENT) < target)
            __builtin_amdgcn_s_sleep(8);
        __threadfence();
    }
    __syncthreads();
}

// P0: fold(31) + transpose(b0..3)   [1039 tasks]
// P1: mm(b0..3) [992] + transpose(b4..7) [1008]  -- HBM-bound and L3-bound mix
// P2: mm(b4..7) [992]
__global__ __launch_bounds__(256, 4) void kfused(const float* __restrict__ x,
                                                 const float* __restrict__ convw,
                                                 const float* __restrict__ gamma,
                                                 const float* __restrict__ beta,
                                                 const float* __restrict__ cb,
                                                 const float* __restrict__ ctxr,
                                                 const float* __restrict__ ctxi,
                                                 u16* __restrict__ xt,
                                                 float* __restrict__ partials,
                                                 u16* __restrict__ wgT2,
                                                 float* __restrict__ wbArr,
                                                 float* __restrict__ wgsArr,
                                                 float* __restrict__ out,
                                                 long long outSize,
                                                 int* __restrict__ bars) {
    __shared__ __align__(16) u16 smem[16000];      // 32,000 B union
    float* fs = (float*)smem;
    const int nbk = (int)gridDim.x;

    for (int t = blockIdx.x; t < 31 + 1008; t += nbk) {
        if (t < 31) {
            fold_task(convw, gamma, beta, wgT2, wbArr, wgsArr, fs, t);
        } else {
            int n = t - 31;
            int bl = n / 252, r2 = n % 252;
            kstat_task(x, xt, partials, smem, r2 % 63, r2 / 63, bl);
        }
    }
    gbar(&bars[0], nbk);

    for (int t = blockIdx.x; t < 992 + 1008; t += nbk) {
        if (t < 992) {
            int bl = t / 248, r = t % 248;
            mm_task(fs, xt, wgT2, partials, wbArr, wgsArr, cb, ctxr, ctxi, out,
                    r / 8, r % 8, bl, outSize);
        } else {
            int n = t - 992;
            int bl = n / 252, r2 = n % 252;
            kstat_task(x, xt, partials, smem, r2 % 63, r2 / 63, 4 + bl);
        }
    }
    gbar(&bars[1], nbk);

    for (int t = blockIdx.x; t < 992; t += nbk) {
        int bl = t / 248, r = t % 248;
        mm_task(fs, xt, wgT2, partials, wbArr, wgsArr, cb, ctxr, ctxi, out,
                r / 8, r % 8, 4 + bl, outSize);
    }
}

// ==================== TIER-2 (r6-proven 3-kernel path) ====================

__global__ __launch_bounds__(256, 4) void kstat(const float* __restrict__ x,
                                                u16* __restrict__ xt,
                                                float* __restrict__ partials,
                                                int b0) {
    const int tw = blockIdx.x, cg = blockIdx.y, bl = blockIdx.z, b = b0 + bl;
    __shared__ __align__(16) u16 tile[32 * 500];
    // reuse the task body with LOCAL slot bl (tier-2 xt sized per group)
    const int tid = threadIdx.x, lane = tid & 63, w = tid >> 6;
    const int NF4 = (tw == 62) ? 62 : 124;
    if (tw == 62) {
        u32* t32 = (u32*)tile;
        for (int n = tid; n < 8000; n += 256) t32[n] = 0;
        __syncthreads();
    }
    const f32x4* src4 = (const f32x4*)(x + (size_t)b * (CC * TT_ * NB));
    const int fbase = tw * 124;
    f32x4 v[16];
    #pragma unroll
    for (int k = 0; k < 8; ++k) {
        const int c = cg * 32 + w * 8 + k;
        const f32x4* p = src4 + (size_t)c * 7750 + fbase;
        int o0 = lane, o1 = 64 + lane;
        o0 = (o0 < NF4) ? o0 : 0;
        o1 = (o1 < NF4) ? o1 : 0;
        v[2 * k]     = p[o0];
        v[2 * k + 1] = p[o1];
    }
    #pragma unroll
    for (int k = 0; k < 16; ++k) asm volatile("" : "+v"(v[k]));
    __builtin_amdgcn_sched_barrier(0);
    #pragma unroll
    for (int k = 0; k < 8; ++k) {
        u16* row = tile + (w * 8 + k) * 500;
        #pragma unroll
        for (int it = 0; it < 2; ++it) {
            const int off = it * 64 + lane;
            f32x4 vv = v[2 * k + it];
            ushort4 pk;
            pk.x = f2bf(vv.x); pk.y = f2bf(vv.y); pk.z = f2bf(vv.z); pk.w = f2bf(vv.w);
            if (off < NF4) *(ushort4*)(row + 4 * off) = pk;
        }
    }
    __syncthreads();
    uint4* dst4 = (uint4*)xt;
    const int t0 = tw * 16;
    for (int n = tid; n < 1984; n += 256) {
        int task = n >> 4, m = n & 15;
        int band = task >> 2, cbl = task & 3;
        int fidx = m * 31 + band;
        u16 e[8];
        #pragma unroll
        for (int j = 0; j < 8; ++j)
            e[j] = tile[(8 * cbl + j) * 500 + fidx];
        uint4 u;
        u.x = (u32)e[0] | ((u32)e[1] << 16);
        u.y = (u32)e[2] | ((u32)e[3] << 16);
        u.z = (u32)e[4] | ((u32)e[5] << 16);
        u.w = (u32)e[6] | ((u32)e[7] << 16);
        dst4[((size_t)(bl * NB + band) * 16 + (cg * 4 + cbl)) * TPAD + t0 + m] = u;
    }
    if (tid < 248) {
        int band = tid >> 3, slot = tid & 7;
        float s = 0.f, sq = 0.f;
        #pragma unroll
        for (int ci = 0; ci < 32; ++ci) {
            #pragma unroll
            for (int d = 0; d < 2; ++d) {
                float f = bf2f(tile[ci * 500 + (2 * slot + d) * 31 + band]);
                s += f; sq += f * f;
            }
        }
        #pragma unroll
        for (int off = 1; off < 8; off <<= 1) {
            s  += __shfl_xor(s, off);
            sq += __shfl_xor(sq, off);
        }
        if (slot == 0) {
            int ch = tw * 4 + cg;
            *(float2*)&partials[((size_t)(b * NB + band) * 256 + ch) * 2] = make_float2(s, sq);
        }
    }
}

__global__ __launch_bounds__(128) void kfoldW(const float* __restrict__ w,
                                              const float* __restrict__ gamma,
                                              const float* __restrict__ beta,
                                              u16* __restrict__ wgT2,
                                              float* __restrict__ wbArr,
                                              float* __restrict__ wgsArr) {
    const int i = blockIdx.x, tid = threadIdx.x;
    __shared__ float g[CC], be[CC];
    g[tid] = gamma[i * CC + tid];
    be[tid] = beta[i * CC + tid];
    __syncthreads();
    const int oc = bandBW(i) * 8;
    float wb = 0.f, wgs = 0.f;
    for (int c = 0; c < CC; ++c) {
        float wv = w[(size_t)(i * MAXOC + tid) * CC + c];
        wb += wv * be[c];
        wgs += wv * g[c];
    }
    wbArr[i * CC + tid] = wb;
    wgsArr[i * CC + tid] = wgs;
    const float gc = g[tid];
    for (int o = 0; o < MAXOC; ++o) {
        float wv = w[(size_t)(i * MAXOC + o) * CC + tid];
        wgT2[(size_t)(i * MAXOC + o) * CC + tid] = (o < oc) ? f2bf(wv * gc) : (u16)0;
    }
}

__global__ __launch_bounds__(256) void kmm(const u16* __restrict__ xt,
                                           const u16* __restrict__ wgT2,
                                           const float* __restrict__ partials,
                                           const float* __restrict__ wbArr,
                                           const float* __restrict__ wgsArr,
                                           const float* __restrict__ cb,
                                           const float* __restrict__ ctxr,
                                           const float* __restrict__ ctxi,
                                           float* __restrict__ out,
                                           int b0, long long outSize) {
    extern __shared__ float smem[];
    float* Y  = smem;
    float* bo = smem + YMAXF;
    float* red = bo + 128;
    const int bx = blockIdx.x, i = blockIdx.y, bl = blockIdx.z, b = b0 + bl;
    if (i < 10 || i == 30)
        kmm_body<32, 2, 2, 1, 4, 128, 1>(Y, bo, red, xt, wgT2, partials, wbArr, wgsArr, cb, ctxr, ctxi, out, i, b, bl, bx, outSize);
    else if (i < 22)
        kmm_body<64, 4, 1, 1, 4, 64, 2>(Y, bo, red, xt, wgT2, partials, wbArr, wgsArr, cb, ctxr, ctxi, out, i, b, bl, bx, outSize);
    else
        kmm_body<128, 4, 1, 2, 2, 32, 4>(Y, bo, red, xt, wgT2, partials, wbArr, wgsArr, cb, ctxr, ctxi, out, i, b, bl, bx, outSize);
}

// ==================== FALLBACK (zero workspace) ====================
template <int ROWS, int RPT, int BCLASS>
__global__ __launch_bounds__(256) void kreal(const float* __restrict__ x,
                                             const float* __restrict__ ctxr,
                                             const float* __restrict__ ctxi,
                                             const float* __restrict__ gamma,
                                             const float* __restrict__ beta,
                                             const float* __restrict__ w,
                                             const float* __restrict__ cb,
                                             float* __restrict__ out,
                                             long long outSize) {
    constexpr int TCH = 64, TPT = 4;
    const int by = blockIdx.x, b = blockIdx.y;
    const int i = (BCLASS == 0) ? (by < 10 ? by : 30) : (BCLASS == 1 ? 10 + by : 22 + by);
    const int tid = threadIdx.x, tx = tid & 15, ty = tid >> 4;

    __shared__ float XN[CC][TCH];
    __shared__ float WT[16][ROWS];
    __shared__ float gl[CC], bt[CC];
    __shared__ float red[8];

    const float* xb = x + (size_t)b * CC * TT_ * NB + i;

    if (tid < CC) { gl[tid] = gamma[i * CC + tid]; bt[tid] = beta[i * CC + tid]; }

    float s = 0.f, sq = 0.f;
    for (int n = tid; n < CC * TT_; n += 256) {
        float v = xb[(size_t)n * NB];
        s += v; sq += v * v;
    }
    #pragma unroll
    for (int off = 1; off < 64; off <<= 1) {
        s  += __shfl_xor(s, off);
        sq += __shfl_xor(sq, off);
    }
    if ((tid & 63) == 0) { red[(tid >> 6) * 2] = s; red[(tid >> 6) * 2 + 1] = sq; }
    __syncthreads();
    s  = red[0] + red[2] + red[4] + red[6];
    sq = red[1] + red[3] + red[5] + red[7];
    const float mean = s * (1.f / 128000.f);
    const float var  = sq * (1.f / 128000.f) - mean * mean;
    const float rstd = rsqrtf(var + 1e-8f);

    const int bw = bandBW(i), F0 = bandF0(i);
    const float* wband = w + (size_t)i * MAXOC * CC;

    for (int t0 = 0; t0 < TT_; t0 += TCH) {
        __syncthreads();
        for (int n = tid; n < CC * TCH; n += 256) {
            int c = n / TCH, tl = n % TCH;
            int t = t0 + tl;
            float v = (t < TT_) ? xb[((size_t)c * TT_ + t) * NB] : 0.f;
            XN[c][tl] = (v - mean) * rstd * gl[c] + bt[c];
        }

        float acc[RPT][TPT];
        #pragma unroll
        for (int r = 0; r < RPT; ++r)
            #pragma unroll
            for (int q = 0; q < TPT; ++q) acc[r][q] = 0.f;

        for (int k0 = 0; k0 < CC; k0 += 16) {
            for (int n = tid; n < 16 * ROWS; n += 256) {
                int kk = n / ROWS, o = n % ROWS;
                WT[kk][o] = wband[(size_t)o * CC + (k0 + kk)];
            }
            __syncthreads();
            #pragma unroll
            for (int kk = 0; kk < 16; ++kk) {
                float wv[RPT], xv[TPT];
                #pragma unroll
                for (int r = 0; r < RPT; ++r) wv[r] = WT[kk][ty * RPT + r];
                #pragma unroll
                for (int q = 0; q < TPT; ++q) xv[q] = XN[k0 + kk][tx * TPT + q];
                #pragma unroll
                for (int r = 0; r < RPT; ++r)
                    #pragma unroll
                    for (int q = 0; q < TPT; ++q) acc[r][q] = fmaf(wv[r], xv[q], acc[r][q]);
            }
            __syncthreads();
        }

        float* Yb = &XN[0][0];
        #pragma unroll
        for (int r = 0; r < RPT; ++r) {
            int o = ty * RPT + r;
            float bv = cb[i * MAXOC + o];
            #pragma unroll
            for (int q = 0; q < TPT; ++q)
                Yb[o * TCH + tx * TPT + q] = fmaxf(acc[r][q] + bv, 0.f);
        }
        __syncthreads();

        const int jobs = 2 * bw * TCH;
        for (int n = tid; n < jobs; n += 256) {
            int tl = n % TCH, sf = n / TCH;
            int ss = sf / bw, f = sf - ss * bw;
            int t = t0 + tl;
            if (t < TT_) {
                float lrv = Yb[(ss * bw + f) * TCH + tl];
                float liv = Yb[(2 * bw + ss * bw + f) * TCH + tl];
                float grv = Yb[(4 * bw + ss * bw + f) * TCH + tl];
                float giv = Yb[(6 * bw + ss * bw + f) * TCH + tl];
                float mr = lrv * (1.f / (1.f + __expf(-grv)));
                float mi = liv * (1.f / (1.f + __expf(-giv)));
                size_t cidx = ((size_t)(i * BB + b) * MAXBW + f) * TT_ + t;
                float cr = ctxr[cidx], ci = ctxi[cidx];
                long long ridx = ((long long)((b * 2 + ss) * 257 + F0 + f)) * TT_ + t;
                if (ridx < outSize) out[ridx] = cr * mr - ci * mi;
            }
        }
    }
}

extern "C" void kernel_launch(void* const* d_in, const int* in_sizes, int n_in,
                              void* d_out, int out_size, void* d_ws, size_t ws_size,
                              hipStream_t stream) {
    const float* sep   = (const float*)d_in[0];
    const float* ctxr  = (const float*)d_in[2];
    const float* ctxi  = (const float*)d_in[3];
    const float* gamma = (const float*)d_in[4];
    const float* beta  = (const float*)d_in[5];
    const float* convw = (const float*)d_in[6];
    const float* convb = (const float*)d_in[7];
    float* out = (float*)d_out;

    long long outSize = (long long)out_size;   // real plane, strictly guarded

    const size_t fixedEnd = 1555456;
    const size_t perB = (size_t)NB * 16 * TPAD * 16;  // 8,126,464 B per batch
    const size_t barsOff = fixedEnd + 8 * perB;       // 66,567,168
    const size_t needFused = barsOff + 256;

    char* ws = (char*)d_ws;
    float* partials = (float*)(ws + 0);          // 8*31*256*2*4 = 507,904 B
    float* wbArr    = (float*)(ws + 507904);
    float* wgsArr   = (float*)(ws + 523776);
    u16*   wgT2     = (u16*)(ws + 539648);       // 1,015,808 B
    u16*   xt       = (u16*)(ws + fixedEnd);

    if (ws_size >= needFused) {
        int* bars = (int*)(ws + barsOff);
        hipMemsetAsync(bars, 0, 64, stream);
        kfused<<<dim3(GRID_P), 256, 0, stream>>>(sep, convw, gamma, beta, convb,
                                                 ctxr, ctxi, xt, partials, wgT2,
                                                 wbArr, wgsArr, out, outSize, bars);
    } else if (ws_size >= fixedEnd + perB) {
        int nbper = (int)((ws_size - fixedEnd) / perB);
        if (nbper > BB) nbper = BB;
        const size_t smemB = (size_t)(YMAXF + 128 + 8) * 4;   // 17,440 B
        kfoldW<<<dim3(NB), 128, 0, stream>>>(convw, gamma, beta, wgT2, wbArr, wgsArr);
        for (int b0 = 0; b0 < BB; b0 += nbper) {
            int nb = (BB - b0 < nbper) ? (BB - b0) : nbper;
            kstat<<<dim3(63, 4, nb), 256, 0, stream>>>(sep, xt, partials, b0);
            kmm<<<dim3(8, NB, nb), 256, smemB, stream>>>(xt, wgT2, partials, wbArr, wgsArr, convb, ctxr, ctxi, out, b0, outSize);
        }
    } else {
        kreal<32, 2, 0><<<dim3(11, BB), 256, 0, stream>>>(sep, ctxr, ctxi, gamma, beta, convw, convb, out, outSize);
        kreal<64, 4, 1><<<dim3(12, BB), 256, 0, stream>>>(sep, ctxr, ctxi, gamma, beta, convw, convb, out, outSize);
        kreal<128, 8, 2><<<dim3(8, BB), 256, 0, stream>>>(sep, ctxr, ctxi, gamma, beta, convw, convb, out, outSize);
    }
}

// Round 8
// 90.945 us; speedup vs baseline: 9.5818x; 9.5818x over previous
//
#include <hip/hip_runtime.h>

typedef unsigned short u16;
typedef unsigned int u32;

#define BB 8
#define CC 128
#define TT_ 1000
#define TPAD 1024
#define NB 31
#define MAXBW 16
#define MAXOC 128

typedef __bf16 bf16x8 __attribute__((ext_vector_type(8)));
typedef float f32x4 __attribute__((ext_vector_type(4)));

__device__ __forceinline__ u16 f2bf(float f) {
    u32 u = __float_as_uint(f);
    return (u16)((u + 0x7fffu + ((u >> 16) & 1u)) >> 16);
}
__device__ __forceinline__ float bf2f(u16 h) { return __uint_as_float(((u32)h) << 16); }
__device__ __forceinline__ int bandBW(int i) { return (i < 10) ? 3 : ((i < 22) ? 8 : ((i < 30) ? 16 : 3)); }
__device__ __forceinline__ int bandF0(int i) {
    return (i < 10) ? 3 * i : ((i < 22) ? 30 + 8 * (i - 10) : ((i < 30) ? 126 + 16 * (i - 22) : 254));
}

// ==================== FULL PATH ====================

// kstat v9 (r4/r6-proven streaming transpose, byte-identical to r6).
// Block = (t-window of 16, c-group of 32, b). 1KB-contiguous read streams,
// lane-linear LDS writes, xt layout [bl][band][cblk 16][t 1024][8c] bf16.
__global__ __launch_bounds__(256, 4) void kstat(const float* __restrict__ x,
                                                u16* __restrict__ xt,
                                                float* __restrict__ partials,
                                                int b0) {
    const int tw = blockIdx.x, cg = blockIdx.y, bl = blockIdx.z, b = b0 + bl;
    const int tid = threadIdx.x, lane = tid & 63, w = tid >> 6;
    __shared__ __align__(16) u16 tile[32 * 500];   // 32,000 B
    const int NF4 = (tw == 62) ? 62 : 124;

    if (tw == 62) {                                // zero-fill pad region
        u32* t32 = (u32*)tile;
        for (int n = tid; n < 8000; n += 256) t32[n] = 0;
        __syncthreads();
    }

    const f32x4* src4 = (const f32x4*)(x + (size_t)b * (CC * TT_ * NB));
    const int fbase = tw * 124;

    // load phase: 16 float4/thread, all issued before any use
    f32x4 v[16];
    #pragma unroll
    for (int k = 0; k < 8; ++k) {
        const int c = cg * 32 + w * 8 + k;
        const f32x4* p = src4 + (size_t)c * 7750 + fbase;
        int o0 = lane, o1 = 64 + lane;
        o0 = (o0 < NF4) ? o0 : 0;
        o1 = (o1 < NF4) ? o1 : 0;
        v[2 * k]     = p[o0];
        v[2 * k + 1] = p[o1];
    }
    #pragma unroll
    for (int k = 0; k < 16; ++k) asm volatile("" : "+v"(v[k]));
    __builtin_amdgcn_sched_barrier(0);

    // convert + LDS write: one b64 per float4, lane-linear
    #pragma unroll
    for (int k = 0; k < 8; ++k) {
        u16* row = tile + (w * 8 + k) * 500;
        #pragma unroll
        for (int it = 0; it < 2; ++it) {
            const int off = it * 64 + lane;
            f32x4 vv = v[2 * k + it];
            ushort4 pk;
            pk.x = f2bf(vv.x); pk.y = f2bf(vv.y); pk.z = f2bf(vv.z); pk.w = f2bf(vv.w);
            if (off < NF4) *(ushort4*)(row + 4 * off) = pk;
        }
    }
    __syncthreads();

    // store pass: gather 8 c's per uint4, 256B runs
    uint4* dst4 = (uint4*)xt;
    const int t0 = tw * 16;
    for (int n = tid; n < 1984; n += 256) {
        int task = n >> 4, m = n & 15;
        int band = task >> 2, cbl = task & 3;
        int fidx = m * 31 + band;
        u16 e[8];
        #pragma unroll
        for (int j = 0; j < 8; ++j)
            e[j] = tile[(8 * cbl + j) * 500 + fidx];
        uint4 u;
        u.x = (u32)e[0] | ((u32)e[1] << 16);
        u.y = (u32)e[2] | ((u32)e[3] << 16);
        u.z = (u32)e[4] | ((u32)e[5] << 16);
        u.w = (u32)e[6] | ((u32)e[7] << 16);
        dst4[((size_t)(bl * NB + band) * 16 + (cg * 4 + cbl)) * TPAD + t0 + m] = u;
    }

    // stats: 8 lanes/band, shfl reduce
    if (tid < 248) {
        int band = tid >> 3, slot = tid & 7;
        float s = 0.f, sq = 0.f;
        #pragma unroll
        for (int ci = 0; ci < 32; ++ci) {
            #pragma unroll
            for (int d = 0; d < 2; ++d) {
                float f = bf2f(tile[ci * 500 + (2 * slot + d) * 31 + band]);
                s += f; sq += f * f;
            }
        }
        #pragma unroll
        for (int off = 1; off < 8; off <<= 1) {
            s  += __shfl_xor(s, off);
            sq += __shfl_xor(sq, off);
        }
        if (slot == 0) {
            int ch = tw * 4 + cg;
            *(float2*)&partials[((size_t)(b * NB + band) * 256 + ch) * 2] = make_float2(s, sq);
        }
    }
}

// kmm v6: foldW merged into the prologue — no wgT2/wbArr/wgsArr.
// Per block: stage gamma/beta in Y's LDS area; compute wb/wgs dots in regs
// (W band-block is L2-resident, shared by all blocks of the band); build
// A-fragments inline as f2bf(W*gamma) (identical rounding to old wgT2).
// Rows >= oc need no zeroing: GLU epilogue reads only Y rows < 8*bw = oc.
// C/D mapping (m89-verified): col = lane&15 (t), row = (lane>>4)*4 + reg (oc).
#define YMAXF 4224
template <int ROWS, int WM, int WN, int RF, int CF, int TSTEP, int NSTEPS>
__device__ __forceinline__ void kmm_body(float* __restrict__ Y, float* __restrict__ bo,
                                         float* __restrict__ red,
                                         const u16* __restrict__ xt,
                                         const float* __restrict__ convw,
                                         const float* __restrict__ gamma,
                                         const float* __restrict__ beta,
                                         const float* __restrict__ partials,
                                         const float* __restrict__ cb,
                                         const float* __restrict__ ctxr,
                                         const float* __restrict__ ctxi,
                                         float* __restrict__ out,
                                         int i, int b, int bl, int bx, long long outSize) {
    const int tid = threadIdx.x;
    const int w = tid >> 6, l = tid & 63;
    const int wm = w % WM, wn = w / WM;
    const int RB = wm * 16 * RF;
    const int CB = wn * 16 * CF;
    const int lr = l & 15, lk = l >> 4;
    constexpr int PITCH = TSTEP + 1;

    // ---- stage gamma/beta in Y area (free until first t-step) ----
    float* gaL = Y;          // [0..127]
    float* beL = Y + 128;    // [128..255]
    if (tid < 128) gaL[tid] = gamma[i * CC + tid];
    else if (tid < 256) beL[tid - 128] = beta[i * CC + (tid - 128)];
    __syncthreads();

    // ---- A fragments: f2bf(W[row][c] * gamma[c]) inline (was wgT2) ----
    const f32x4* wb4f = (const f32x4*)(convw + (size_t)i * MAXOC * CC);
    const int cbase = lk * 8;
    bf16x8 a[RF][4];
    #pragma unroll
    for (int rf = 0; rf < RF; ++rf) {
        const int row = RB + rf * 16 + lr;
        #pragma unroll
        for (int ks = 0; ks < 4; ++ks) {
            const int c0 = cbase + ks * 32;
            f32x4 w0 = wb4f[row * 32 + (c0 >> 2)];
            f32x4 w1 = wb4f[row * 32 + (c0 >> 2) + 1];
            uint4 pk;
            pk.x = (u32)f2bf(w0.x * gaL[c0])     | ((u32)f2bf(w0.y * gaL[c0 + 1]) << 16);
            pk.y = (u32)f2bf(w0.z * gaL[c0 + 2]) | ((u32)f2bf(w0.w * gaL[c0 + 3]) << 16);
            pk.z = (u32)f2bf(w1.x * gaL[c0 + 4]) | ((u32)f2bf(w1.y * gaL[c0 + 5]) << 16);
            pk.w = (u32)f2bf(w1.z * gaL[c0 + 6]) | ((u32)f2bf(w1.w * gaL[c0 + 7]) << 16);
            a[rf][ks] = __builtin_bit_cast(bf16x8, pk);
        }
    }

    // ---- wb/wgs dot products for this thread's row (was kfoldW part 1) ----
    float wb = 0.f, wgs = 0.f;
    if (tid < ROWS) {
        const float* wrow = convw + ((size_t)i * MAXOC + tid) * CC;
        #pragma unroll 4
        for (int c = 0; c < CC; ++c) {
            float wv = wrow[c];
            wb  += wv * beL[c];
            wgs += wv * gaL[c];
        }
    }

    // ---- fused stats reduction ----
    float s = 0.f, sq = 0.f;
    for (int n = tid; n < 252; n += 256) {
        float2 p = *(const float2*)&partials[((size_t)(b * NB + i) * 256 + n) * 2];
        s += p.x; sq += p.y;
    }
    #pragma unroll
    for (int off = 1; off < 64; off <<= 1) {
        s  += __shfl_xor(s, off);
        sq += __shfl_xor(sq, off);
    }
    if ((tid & 63) == 0) {
        red[(tid >> 6) * 2]     = s;
        red[(tid >> 6) * 2 + 1] = sq;
    }
    __syncthreads();
    s  = red[0] + red[2] + red[4] + red[6];
    sq = red[1] + red[3] + red[5] + red[7];
    const float mean = s * (1.f / 128000.f);
    const float var  = sq * (1.f / 128000.f) - mean * mean;
    const float rstd = rsqrtf(var + 1e-8f);
    if (tid < ROWS)
        bo[tid] = cb[i * MAXOC + tid] + wb - mean * rstd * wgs;

    const uint4* xb4 = ((const uint4*)xt) + (size_t)(bl * NB + i) * 16 * TPAD;
    const int bw = bandBW(i), F0 = bandF0(i);

    for (int st = 0; st < NSTEPS; ++st) {
        const int t0 = (bx * NSTEPS + st) * TSTEP;
        __syncthreads();   // Y free (prologue gaL/beL reads + prev epilogue done)

        // B fragments (blocked-c layout: cblk = lk + 4*ks)
        bf16x8 bf[CF][4];
        #pragma unroll
        for (int cf = 0; cf < CF; ++cf)
            #pragma unroll
            for (int ks = 0; ks < 4; ++ks)
                bf[cf][ks] = __builtin_bit_cast(bf16x8,
                    xb4[(size_t)(lk + ks * 4) * TPAD + (t0 + CB + cf * 16 + lr)]);

        f32x4 acc[RF][CF];
        #pragma unroll
        for (int rf = 0; rf < RF; ++rf)
            #pragma unroll
            for (int cf = 0; cf < CF; ++cf)
                acc[rf][cf] = (f32x4){0.f, 0.f, 0.f, 0.f};

        #pragma unroll
        for (int ks = 0; ks < 4; ++ks)
            #pragma unroll
            for (int rf = 0; rf < RF; ++rf)
                #pragma unroll
                for (int cf = 0; cf < CF; ++cf)
                    acc[rf][cf] = __builtin_amdgcn_mfma_f32_16x16x32_bf16(
                        a[rf][ks], bf[cf][ks], acc[rf][cf], 0, 0, 0);

        // scale + bias + relu -> Y
        #pragma unroll
        for (int rf = 0; rf < RF; ++rf)
            #pragma unroll
            for (int cf = 0; cf < CF; ++cf)
                #pragma unroll
                for (int r = 0; r < 4; ++r) {
                    int row = RB + rf * 16 + lk * 4 + r;
                    float vv = rstd * acc[rf][cf][r] + bo[row];
                    Y[row * PITCH + CB + cf * 16 + lr] = fmaxf(vv, 0.f);
                }
        __syncthreads();

        // GLU + complex mask; REAL plane only, guarded
        const int jobs = 2 * bw * TSTEP;
        for (int n = tid; n < jobs; n += 256) {
            int tl = n % TSTEP, sf = n / TSTEP;
            int ss = sf / bw, f = sf - ss * bw;
            int t = t0 + tl;
            if (t < TT_) {
                float lrv = Y[(ss * bw + f) * PITCH + tl];
                float liv = Y[(2 * bw + ss * bw + f) * PITCH + tl];
                float grv = Y[(4 * bw + ss * bw + f) * PITCH + tl];
                float giv = Y[(6 * bw + ss * bw + f) * PITCH + tl];
                float mr = lrv * (1.f / (1.f + __expf(-grv)));
                float mi = liv * (1.f / (1.f + __expf(-giv)));
                size_t cidx = ((size_t)(i * BB + b) * MAXBW + f) * TT_ + t;
                float cr = ctxr[cidx], ci = ctxi[cidx];
                long long ridx = ((long long)((b * 2 + ss) * 257 + F0 + f)) * TT_ + t;
                if (ridx < outSize) out[ridx] = cr * mr - ci * mi;
            }
        }
    }
}

__global__ __launch_bounds__(256) void kmm(const u16* __restrict__ xt,
                                           const float* __restrict__ convw,
                                           const float* __restrict__ gamma,
                                           const float* __restrict__ beta,
                                           const float* __restrict__ partials,
                                           const float* __restrict__ cb,
                                           const float* __restrict__ ctxr,
                                           const float* __restrict__ ctxi,
                                           float* __restrict__ out,
                                           int b0, long long outSize) {
    extern __shared__ float smem[];
    float* Y  = smem;
    float* bo = smem + YMAXF;
    float* red = bo + 128;
    const int bx = blockIdx.x, i = blockIdx.y, bl = blockIdx.z, b = b0 + bl;
    if (i < 10 || i == 30)
        kmm_body<32, 2, 2, 1, 4, 128, 1>(Y, bo, red, xt, convw, gamma, beta, partials, cb, ctxr, ctxi, out, i, b, bl, bx, outSize);
    else if (i < 22)
        kmm_body<64, 4, 1, 1, 4, 64, 2>(Y, bo, red, xt, convw, gamma, beta, partials, cb, ctxr, ctxi, out, i, b, bl, bx, outSize);
    else
        kmm_body<128, 4, 1, 2, 2, 32, 4>(Y, bo, red, xt, convw, gamma, beta, partials, cb, ctxr, ctxi, out, i, b, bl, bx, outSize);
}

// ==================== FALLBACK (zero workspace) ====================
template <int ROWS, int RPT, int BCLASS>
__global__ __launch_bounds__(256) void kreal(const float* __restrict__ x,
                                             const float* __restrict__ ctxr,
                                             const float* __restrict__ ctxi,
                                             const float* __restrict__ gamma,
                                             const float* __restrict__ beta,
                                             const float* __restrict__ w,
                                             const float* __restrict__ cb,
                                             float* __restrict__ out,
                                             long long outSize) {
    constexpr int TCH = 64, TPT = 4;
    const int by = blockIdx.x, b = blockIdx.y;
    const int i = (BCLASS == 0) ? (by < 10 ? by : 30) : (BCLASS == 1 ? 10 + by : 22 + by);
    const int tid = threadIdx.x, tx = tid & 15, ty = tid >> 4;

    __shared__ float XN[CC][TCH];
    __shared__ float WT[16][ROWS];
    __shared__ float gl[CC], bt[CC];
    __shared__ float red[8];

    const float* xb = x + (size_t)b * CC * TT_ * NB + i;

    if (tid < CC) { gl[tid] = gamma[i * CC + tid]; bt[tid] = beta[i * CC + tid]; }

    float s = 0.f, sq = 0.f;
    for (int n = tid; n < CC * TT_; n += 256) {
        float v = xb[(size_t)n * NB];
        s += v; sq += v * v;
    }
    #pragma unroll
    for (int off = 1; off < 64; off <<= 1) {
        s  += __shfl_xor(s, off);
        sq += __shfl_xor(sq, off);
    }
    if ((tid & 63) == 0) { red[(tid >> 6) * 2] = s; red[(tid >> 6) * 2 + 1] = sq; }
    __syncthreads();
    s  = red[0] + red[2] + red[4] + red[6];
    sq = red[1] + red[3] + red[5] + red[7];
    const float mean = s * (1.f / 128000.f);
    const float var  = sq * (1.f / 128000.f) - mean * mean;
    const float rstd = rsqrtf(var + 1e-8f);

    const int bw = bandBW(i), F0 = bandF0(i);
    const float* wband = w + (size_t)i * MAXOC * CC;

    for (int t0 = 0; t0 < TT_; t0 += TCH) {
        __syncthreads();
        for (int n = tid; n < CC * TCH; n += 256) {
            int c = n / TCH, tl = n % TCH;
            int t = t0 + tl;
            float v = (t < TT_) ? xb[((size_t)c * TT_ + t) * NB] : 0.f;
            XN[c][tl] = (v - mean) * rstd * gl[c] + bt[c];
        }

        float acc[RPT][TPT];
        #pragma unroll
        for (int r = 0; r < RPT; ++r)
            #pragma unroll
            for (int q = 0; q < TPT; ++q) acc[r][q] = 0.f;

        for (int k0 = 0; k0 < CC; k0 += 16) {
            for (int n = tid; n < 16 * ROWS; n += 256) {
                int kk = n / ROWS, o = n % ROWS;
                WT[kk][o] = wband[(size_t)o * CC + (k0 + kk)];
            }
            __syncthreads();
            #pragma unroll
            for (int kk = 0; kk < 16; ++kk) {
                float wv[RPT], xv[TPT];
                #pragma unroll
                for (int r = 0; r < RPT; ++r) wv[r] = WT[kk][ty * RPT + r];
                #pragma unroll
                for (int q = 0; q < TPT; ++q) xv[q] = XN[k0 + kk][tx * TPT + q];
                #pragma unroll
                for (int r = 0; r < RPT; ++r)
                    #pragma unroll
                    for (int q = 0; q < TPT; ++q) acc[r][q] = fmaf(wv[r], xv[q], acc[r][q]);
            }
            __syncthreads();
        }

        float* Yb = &XN[0][0];
        #pragma unroll
        for (int r = 0; r < RPT; ++r) {
            int o = ty * RPT + r;
            float bv = cb[i * MAXOC + o];
            #pragma unroll
            for (int q = 0; q < TPT; ++q)
                Yb[o * TCH + tx * TPT + q] = fmaxf(acc[r][q] + bv, 0.f);
        }
        __syncthreads();

        const int jobs = 2 * bw * TCH;
        for (int n = tid; n < jobs; n += 256) {
            int tl = n % TCH, sf = n / TCH;
            int ss = sf / bw, f = sf - ss * bw;
            int t = t0 + tl;
            if (t < TT_) {
                float lrv = Yb[(ss * bw + f) * TCH + tl];
                float liv = Yb[(2 * bw + ss * bw + f) * TCH + tl];
                float grv = Yb[(4 * bw + ss * bw + f) * TCH + tl];
                float giv = Yb[(6 * bw + ss * bw + f) * TCH + tl];
                float mr = lrv * (1.f / (1.f + __expf(-grv)));
                float mi = liv * (1.f / (1.f + __expf(-giv)));
                size_t cidx = ((size_t)(i * BB + b) * MAXBW + f) * TT_ + t;
                float cr = ctxr[cidx], ci = ctxi[cidx];
                long long ridx = ((long long)((b * 2 + ss) * 257 + F0 + f)) * TT_ + t;
                if (ridx < outSize) out[ridx] = cr * mr - ci * mi;
            }
        }
    }
}

extern "C" void kernel_launch(void* const* d_in, const int* in_sizes, int n_in,
                              void* d_out, int out_size, void* d_ws, size_t ws_size,
                              hipStream_t stream) {
    const float* sep   = (const float*)d_in[0];
    const float* ctxr  = (const float*)d_in[2];
    const float* ctxi  = (const float*)d_in[3];
    const float* gamma = (const float*)d_in[4];
    const float* beta  = (const float*)d_in[5];
    const float* convw = (const float*)d_in[6];
    const float* convb = (const float*)d_in[7];
    float* out = (float*)d_out;

    long long outSize = (long long)out_size;   // real plane, strictly guarded

    const size_t fixedEnd = 507904;                    // partials only
    const size_t perB = (size_t)NB * 16 * TPAD * 16;   // 8,126,464 B per batch

    if (ws_size >= fixedEnd + perB) {
        char* ws = (char*)d_ws;
        float* partials = (float*)(ws + 0);            // 8*31*256*2*4 = 507,904 B
        u16*   xt       = (u16*)(ws + fixedEnd);

        int nbper = (int)((ws_size - fixedEnd) / perB);
        if (nbper > BB) nbper = BB;

        const size_t smemB = (size_t)(YMAXF + 128 + 8) * 4;   // 17,440 B

        for (int b0 = 0; b0 < BB; b0 += nbper) {
            int nb = (BB - b0 < nbper) ? (BB - b0) : nbper;
            kstat<<<dim3(63, 4, nb), 256, 0, stream>>>(sep, xt, partials, b0);
            kmm<<<dim3(8, NB, nb), 256, smemB, stream>>>(xt, convw, gamma, beta, partials, convb, ctxr, ctxi, out, b0, outSize);
        }
    } else {
        kreal<32, 2, 0><<<dim3(11, BB), 256, 0, stream>>>(sep, ctxr, ctxi, gamma, beta, convw, convb, out, outSize);
        kreal<64, 4, 1><<<dim3(12, BB), 256, 0, stream>>>(sep, ctxr, ctxi, gamma, beta, convw, convb, out, outSize);
        kreal<128, 8, 2><<<dim3(8, BB), 256, 0, stream>>>(sep, ctxr, ctxi, gamma, beta, convw, convb, out, outSize);
    }
}

// Round 9
// 87.872 us; speedup vs baseline: 9.9168x; 1.0350x over previous
//
#include <hip/hip_runtime.h>

typedef unsigned short u16;
typedef unsigned int u32;

#define BB 8
#define CC 128
#define TT_ 1000
#define TPAD 1024
#define NB 31
#define MAXBW 16
#define MAXOC 128

typedef __bf16 bf16x8 __attribute__((ext_vector_type(8)));
typedef float f32x4 __attribute__((ext_vector_type(4)));

__device__ __forceinline__ u16 f2bf(float f) {
    u32 u = __float_as_uint(f);
    return (u16)((u + 0x7fffu + ((u >> 16) & 1u)) >> 16);
}
__device__ __forceinline__ float bf2f(u16 h) { return __uint_as_float(((u32)h) << 16); }
__device__ __forceinline__ int bandBW(int i) { return (i < 10) ? 3 : ((i < 22) ? 8 : ((i < 30) ? 16 : 3)); }
__device__ __forceinline__ int bandF0(int i) {
    return (i < 10) ? 3 * i : ((i < 22) ? 30 + 8 * (i - 10) : ((i < 30) ? 126 + 16 * (i - 22) : 254));
}

// ==================== FULL PATH ====================

// kstat v9 (r4/r6-proven streaming transpose, unchanged).
__global__ __launch_bounds__(256, 4) void kstat(const float* __restrict__ x,
                                                u16* __restrict__ xt,
                                                float* __restrict__ partials,
                                                int b0) {
    const int tw = blockIdx.x, cg = blockIdx.y, bl = blockIdx.z, b = b0 + bl;
    const int tid = threadIdx.x, lane = tid & 63, w = tid >> 6;
    __shared__ __align__(16) u16 tile[32 * 500];   // 32,000 B
    const int NF4 = (tw == 62) ? 62 : 124;

    if (tw == 62) {                                // zero-fill pad region
        u32* t32 = (u32*)tile;
        for (int n = tid; n < 8000; n += 256) t32[n] = 0;
        __syncthreads();
    }

    const f32x4* src4 = (const f32x4*)(x + (size_t)b * (CC * TT_ * NB));
    const int fbase = tw * 124;

    // load phase: 16 float4/thread, all issued before any use
    f32x4 v[16];
    #pragma unroll
    for (int k = 0; k < 8; ++k) {
        const int c = cg * 32 + w * 8 + k;
        const f32x4* p = src4 + (size_t)c * 7750 + fbase;
        int o0 = lane, o1 = 64 + lane;
        o0 = (o0 < NF4) ? o0 : 0;
        o1 = (o1 < NF4) ? o1 : 0;
        v[2 * k]     = p[o0];
        v[2 * k + 1] = p[o1];
    }
    #pragma unroll
    for (int k = 0; k < 16; ++k) asm volatile("" : "+v"(v[k]));
    __builtin_amdgcn_sched_barrier(0);

    // convert + LDS write: one b64 per float4, lane-linear
    #pragma unroll
    for (int k = 0; k < 8; ++k) {
        u16* row = tile + (w * 8 + k) * 500;
        #pragma unroll
        for (int it = 0; it < 2; ++it) {
            const int off = it * 64 + lane;
            f32x4 vv = v[2 * k + it];
            ushort4 pk;
            pk.x = f2bf(vv.x); pk.y = f2bf(vv.y); pk.z = f2bf(vv.z); pk.w = f2bf(vv.w);
            if (off < NF4) *(ushort4*)(row + 4 * off) = pk;
        }
    }
    __syncthreads();

    // store pass: gather 8 c's per uint4, 256B runs
    uint4* dst4 = (uint4*)xt;
    const int t0 = tw * 16;
    for (int n = tid; n < 1984; n += 256) {
        int task = n >> 4, m = n & 15;
        int band = task >> 2, cbl = task & 3;
        int fidx = m * 31 + band;
        u16 e[8];
        #pragma unroll
        for (int j = 0; j < 8; ++j)
            e[j] = tile[(8 * cbl + j) * 500 + fidx];
        uint4 u;
        u.x = (u32)e[0] | ((u32)e[1] << 16);
        u.y = (u32)e[2] | ((u32)e[3] << 16);
        u.z = (u32)e[4] | ((u32)e[5] << 16);
        u.w = (u32)e[6] | ((u32)e[7] << 16);
        dst4[((size_t)(bl * NB + band) * 16 + (cg * 4 + cbl)) * TPAD + t0 + m] = u;
    }

    // stats: 8 lanes/band, shfl reduce
    if (tid < 248) {
        int band = tid >> 3, slot = tid & 7;
        float s = 0.f, sq = 0.f;
        #pragma unroll
        for (int ci = 0; ci < 32; ++ci) {
            #pragma unroll
            for (int d = 0; d < 2; ++d) {
                float f = bf2f(tile[ci * 500 + (2 * slot + d) * 31 + band]);
                s += f; sq += f * f;
            }
        }
        #pragma unroll
        for (int off = 1; off < 8; off <<= 1) {
            s  += __shfl_xor(s, off);
            sq += __shfl_xor(sq, off);
        }
        if (slot == 0) {
            int ch = tw * 4 + cg;
            *(float2*)&partials[((size_t)(b * NB + band) * 256 + ch) * 2] = make_float2(s, sq);
        }
    }
}

// kfoldW (standalone, once per run — r6-proven; fused variant regressed in r8).
__global__ __launch_bounds__(128) void kfoldW(const float* __restrict__ w,
                                              const float* __restrict__ gamma,
                                              const float* __restrict__ beta,
                                              u16* __restrict__ wgT2,
                                              float* __restrict__ wbArr,
                                              float* __restrict__ wgsArr) {
    const int i = blockIdx.x, tid = threadIdx.x;
    __shared__ float g[CC], be[CC];
    g[tid] = gamma[i * CC + tid];
    be[tid] = beta[i * CC + tid];
    __syncthreads();
    const int oc = bandBW(i) * 8;
    float wb = 0.f, wgs = 0.f;
    for (int c = 0; c < CC; ++c) {
        float wv = w[(size_t)(i * MAXOC + tid) * CC + c];
        wb += wv * be[c];
        wgs += wv * g[c];
    }
    wbArr[i * CC + tid] = wb;
    wgsArr[i * CC + tid] = wgs;
    const float gc = g[tid];
    for (int o = 0; o < MAXOC; ++o) {
        float wv = w[(size_t)(i * MAXOC + o) * CC + tid];
        wgT2[(size_t)(i * MAXOC + o) * CC + tid] = (o < oc) ? f2bf(wv * gc) : (u16)0;
    }
}

// kmm v7: IN-REGISTER GLU epilogue via A-row permutation.
// Permuting A's rows permutes D's rows identically (D row r = A row r x B).
// Map tile row r -> logical W row (r&3)*2bw + (r>>2): each lane's 4 acc regs
// (rows lk*4..lk*4+3, m89-verified C/D layout) hold the GLU quad
// {q, 2bw+q, 4bw+q, 6bw+q} for quad q = RB/4 + rf*4 + lk = s*bw+f.
// -> bias+relu+sigmoid+mask+store all in registers. No Y LDS, no per-step
// barriers. wgT2 rows >= oc are zero -> invalid quads (class A) read zeros
// and are store-masked.
template <int ROWS, int WM, int WN, int RF, int CF, int TSTEP, int NSTEPS>
__device__ __forceinline__ void kmm_body(float* __restrict__ bo, float* __restrict__ red,
                                         const u16* __restrict__ xt,
                                         const u16* __restrict__ wgT2,
                                         const float* __restrict__ partials,
                                         const float* __restrict__ wbArr,
                                         const float* __restrict__ wgsArr,
                                         const float* __restrict__ cb,
                                         const float* __restrict__ ctxr,
                                         const float* __restrict__ ctxi,
                                         float* __restrict__ out,
                                         int i, int b, int bl, int bx, long long outSize) {
    const int tid = threadIdx.x;
    const int w = tid >> 6, l = tid & 63;
    const int wm = w % WM, wn = w / WM;
    const int RB = wm * 16 * RF;
    const int CB = wn * 16 * CF;
    const int lr = l & 15, lk = l >> 4;
    const int bw = bandBW(i), F0 = bandF0(i);

    // A fragments with GLU row permutation (overlaps the stats reduce)
    const uint4* wb4 = (const uint4*)(wgT2 + (size_t)i * MAXOC * CC);
    bf16x8 a[RF][4];
    #pragma unroll
    for (int rf = 0; rf < RF; ++rf) {
        const int rt = RB + rf * 16 + lr;
        const int lrow = (rt & 3) * 2 * bw + (rt >> 2);
        #pragma unroll
        for (int ks = 0; ks < 4; ++ks)
            a[rf][ks] = __builtin_bit_cast(bf16x8,
                wb4[(lrow * CC + lk * 8 + ks * 32) >> 3]);
    }

    // fused stats reduction
    float s = 0.f, sq = 0.f;
    for (int n = tid; n < 252; n += 256) {
        float2 p = *(const float2*)&partials[((size_t)(b * NB + i) * 256 + n) * 2];
        s += p.x; sq += p.y;
    }
    #pragma unroll
    for (int off = 1; off < 64; off <<= 1) {
        s  += __shfl_xor(s, off);
        sq += __shfl_xor(sq, off);
    }
    if ((tid & 63) == 0) {
        red[(tid >> 6) * 2]     = s;
        red[(tid >> 6) * 2 + 1] = sq;
    }
    __syncthreads();
    s  = red[0] + red[2] + red[4] + red[6];
    sq = red[1] + red[3] + red[5] + red[7];
    const float mean = s * (1.f / 128000.f);
    const float var  = sq * (1.f / 128000.f) - mean * mean;
    const float rstd = rsqrtf(var + 1e-8f);
    if (tid < ROWS)
        bo[tid] = cb[i * MAXOC + tid] + wbArr[i * CC + tid] - mean * rstd * wgsArr[i * CC + tid];
    __syncthreads();

    // per-rf quad info (bias quad, ctx/out row offsets, validity)
    bool  qv[RF];
    float bq[RF][4];
    size_t coff[RF];
    long long roff[RF];
    #pragma unroll
    for (int rf = 0; rf < RF; ++rf) {
        int q = RB / 4 + rf * 4 + lk;
        qv[rf] = (q < 2 * bw);
        int qc = qv[rf] ? q : 0;
        int ss = (qc >= bw) ? 1 : 0;
        int f  = qc - ss * bw;
        bq[rf][0] = bo[qc];
        bq[rf][1] = bo[2 * bw + qc];
        bq[rf][2] = bo[4 * bw + qc];
        bq[rf][3] = bo[6 * bw + qc];
        coff[rf] = ((size_t)(i * BB + b) * MAXBW + f) * TT_;
        roff[rf] = ((long long)((b * 2 + ss) * 257 + F0 + f)) * TT_;
    }

    const uint4* xb4 = ((const uint4*)xt) + (size_t)(bl * NB + i) * 16 * TPAD;

    for (int st = 0; st < NSTEPS; ++st) {
        const int t0 = (bx * NSTEPS + st) * TSTEP;

        // B fragments (blocked-c layout: cblk = lk + 4*ks)
        bf16x8 bf[CF][4];
        #pragma unroll
        for (int cf = 0; cf < CF; ++cf)
            #pragma unroll
            for (int ks = 0; ks < 4; ++ks)
                bf[cf][ks] = __builtin_bit_cast(bf16x8,
                    xb4[(size_t)(lk + ks * 4) * TPAD + (t0 + CB + cf * 16 + lr)]);

        f32x4 acc[RF][CF];
        #pragma unroll
        for (int rf = 0; rf < RF; ++rf)
            #pragma unroll
            for (int cf = 0; cf < CF; ++cf)
                acc[rf][cf] = (f32x4){0.f, 0.f, 0.f, 0.f};

        #pragma unroll
        for (int ks = 0; ks < 4; ++ks)
            #pragma unroll
            for (int rf = 0; rf < RF; ++rf)
                #pragma unroll
                for (int cf = 0; cf < CF; ++cf)
                    acc[rf][cf] = __builtin_amdgcn_mfma_f32_16x16x32_bf16(
                        a[rf][ks], bf[cf][ks], acc[rf][cf], 0, 0, 0);

        // in-register epilogue: bias+relu -> GLU -> complex mask -> store
        #pragma unroll
        for (int rf = 0; rf < RF; ++rf)
            #pragma unroll
            for (int cf = 0; cf < CF; ++cf) {
                const int t = t0 + CB + cf * 16 + lr;
                if (qv[rf] && t < TT_) {
                    float a0 = fmaxf(rstd * acc[rf][cf][0] + bq[rf][0], 0.f);
                    float a1 = fmaxf(rstd * acc[rf][cf][1] + bq[rf][1], 0.f);
                    float a2 = fmaxf(rstd * acc[rf][cf][2] + bq[rf][2], 0.f);
                    float a3 = fmaxf(rstd * acc[rf][cf][3] + bq[rf][3], 0.f);
                    float mr = a0 * (1.f / (1.f + __expf(-a2)));
                    float mi = a1 * (1.f / (1.f + __expf(-a3)));
                    float cr = ctxr[coff[rf] + t];
                    float ci = ctxi[coff[rf] + t];
                    long long ridx = roff[rf] + t;
                    if (ridx < outSize) out[ridx] = cr * mr - ci * mi;
                }
            }
    }
}

__global__ __launch_bounds__(256) void kmm(const u16* __restrict__ xt,
                                           const u16* __restrict__ wgT2,
                                           const float* __restrict__ partials,
                                           const float* __restrict__ wbArr,
                                           const float* __restrict__ wgsArr,
                                           const float* __restrict__ cb,
                                           const float* __restrict__ ctxr,
                                           const float* __restrict__ ctxi,
                                           float* __restrict__ out,
                                           int b0, long long outSize) {
    __shared__ float bo[128];
    __shared__ float red[8];
    const int bx = blockIdx.x, i = blockIdx.y, bl = blockIdx.z, b = b0 + bl;
    if (i < 10 || i == 30)
        kmm_body<32, 2, 2, 1, 4, 128, 1>(bo, red, xt, wgT2, partials, wbArr, wgsArr, cb, ctxr, ctxi, out, i, b, bl, bx, outSize);
    else if (i < 22)
        kmm_body<64, 4, 1, 1, 4, 64, 2>(bo, red, xt, wgT2, partials, wbArr, wgsArr, cb, ctxr, ctxi, out, i, b, bl, bx, outSize);
    else
        kmm_body<128, 4, 1, 2, 2, 32, 4>(bo, red, xt, wgT2, partials, wbArr, wgsArr, cb, ctxr, ctxi, out, i, b, bl, bx, outSize);
}

// ==================== FALLBACK (zero workspace) ====================
template <int ROWS, int RPT, int BCLASS>
__global__ __launch_bounds__(256) void kreal(const float* __restrict__ x,
                                             const float* __restrict__ ctxr,
                                             const float* __restrict__ ctxi,
                                             const float* __restrict__ gamma,
                                             const float* __restrict__ beta,
                                             const float* __restrict__ w,
                                             const float* __restrict__ cb,
                                             float* __restrict__ out,
                                             long long outSize) {
    constexpr int TCH = 64, TPT = 4;
    const int by = blockIdx.x, b = blockIdx.y;
    const int i = (BCLASS == 0) ? (by < 10 ? by : 30) : (BCLASS == 1 ? 10 + by : 22 + by);
    const int tid = threadIdx.x, tx = tid & 15, ty = tid >> 4;

    __shared__ float XN[CC][TCH];
    __shared__ float WT[16][ROWS];
    __shared__ float gl[CC], bt[CC];
    __shared__ float red[8];

    const float* xb = x + (size_t)b * CC * TT_ * NB + i;

    if (tid < CC) { gl[tid] = gamma[i * CC + tid]; bt[tid] = beta[i * CC + tid]; }

    float s = 0.f, sq = 0.f;
    for (int n = tid; n < CC * TT_; n += 256) {
        float v = xb[(size_t)n * NB];
        s += v; sq += v * v;
    }
    #pragma unroll
    for (int off = 1; off < 64; off <<= 1) {
        s  += __shfl_xor(s, off);
        sq += __shfl_xor(sq, off);
    }
    if ((tid & 63) == 0) { red[(tid >> 6) * 2] = s; red[(tid >> 6) * 2 + 1] = sq; }
    __syncthreads();
    s  = red[0] + red[2] + red[4] + red[6];
    sq = red[1] + red[3] + red[5] + red[7];
    const float mean = s * (1.f / 128000.f);
    const float var  = sq * (1.f / 128000.f) - mean * mean;
    const float rstd = rsqrtf(var + 1e-8f);

    const int bw = bandBW(i), F0 = bandF0(i);
    const float* wband = w + (size_t)i * MAXOC * CC;

    for (int t0 = 0; t0 < TT_; t0 += TCH) {
        __syncthreads();
        for (int n = tid; n < CC * TCH; n += 256) {
            int c = n / TCH, tl = n % TCH;
            int t = t0 + tl;
            float v = (t < TT_) ? xb[((size_t)c * TT_ + t) * NB] : 0.f;
            XN[c][tl] = (v - mean) * rstd * gl[c] + bt[c];
        }

        float acc[RPT][TPT];
        #pragma unroll
        for (int r = 0; r < RPT; ++r)
            #pragma unroll
            for (int q = 0; q < TPT; ++q) acc[r][q] = 0.f;

        for (int k0 = 0; k0 < CC; k0 += 16) {
            for (int n = tid; n < 16 * ROWS; n += 256) {
                int kk = n / ROWS, o = n % ROWS;
                WT[kk][o] = wband[(size_t)o * CC + (k0 + kk)];
            }
            __syncthreads();
            #pragma unroll
            for (int kk = 0; kk < 16; ++kk) {
                float wv[RPT], xv[TPT];
                #pragma unroll
                for (int r = 0; r < RPT; ++r) wv[r] = WT[kk][ty * RPT + r];
                #pragma unroll
                for (int q = 0; q < TPT; ++q) xv[q] = XN[k0 + kk][tx * TPT + q];
                #pragma unroll
                for (int r = 0; r < RPT; ++r)
                    #pragma unroll
                    for (int q = 0; q < TPT; ++q) acc[r][q] = fmaf(wv[r], xv[q], acc[r][q]);
            }
            __syncthreads();
        }

        float* Yb = &XN[0][0];
        #pragma unroll
        for (int r = 0; r < RPT; ++r) {
            int o = ty * RPT + r;
            float bv = cb[i * MAXOC + o];
            #pragma unroll
            for (int q = 0; q < TPT; ++q)
                Yb[o * TCH + tx * TPT + q] = fmaxf(acc[r][q] + bv, 0.f);
        }
        __syncthreads();

        const int jobs = 2 * bw * TCH;
        for (int n = tid; n < jobs; n += 256) {
            int tl = n % TCH, sf = n / TCH;
            int ss = sf / bw, f = sf - ss * bw;
            int t = t0 + tl;
            if (t < TT_) {
                float lrv = Yb[(ss * bw + f) * TCH + tl];
                float liv = Yb[(2 * bw + ss * bw + f) * TCH + tl];
                float grv = Yb[(4 * bw + ss * bw + f) * TCH + tl];
                float giv = Yb[(6 * bw + ss * bw + f) * TCH + tl];
                float mr = lrv * (1.f / (1.f + __expf(-grv)));
                float mi = liv * (1.f / (1.f + __expf(-giv)));
                size_t cidx = ((size_t)(i * BB + b) * MAXBW + f) * TT_ + t;
                float cr = ctxr[cidx], ci = ctxi[cidx];
                long long ridx = ((long long)((b * 2 + ss) * 257 + F0 + f)) * TT_ + t;
                if (ridx < outSize) out[ridx] = cr * mr - ci * mi;
            }
        }
    }
}

extern "C" void kernel_launch(void* const* d_in, const int* in_sizes, int n_in,
                              void* d_out, int out_size, void* d_ws, size_t ws_size,
                              hipStream_t stream) {
    const float* sep   = (const float*)d_in[0];
    const float* ctxr  = (const float*)d_in[2];
    const float* ctxi  = (const float*)d_in[3];
    const float* gamma = (const float*)d_in[4];
    const float* beta  = (const float*)d_in[5];
    const float* convw = (const float*)d_in[6];
    const float* convb = (const float*)d_in[7];
    float* out = (float*)d_out;

    long long outSize = (long long)out_size;   // real plane, strictly guarded

    const size_t fixedEnd = 1555456;
    const size_t perB = (size_t)NB * 16 * TPAD * 16;  // 8,126,464 B per batch

    if (ws_size >= fixedEnd + perB) {
        char* ws = (char*)d_ws;
        float* partials = (float*)(ws + 0);          // 8*31*256*2*4 = 507,904 B
        float* wbArr    = (float*)(ws + 507904);     // 15,872 B
        float* wgsArr   = (float*)(ws + 523776);     // 15,872 B
        u16*   wgT2     = (u16*)(ws + 539648);       // 31*128*128*2 = 1,015,808 B
        u16*   xt       = (u16*)(ws + 1555456);

        int nbper = (int)((ws_size - fixedEnd) / perB);
        if (nbper > BB) nbper = BB;

        kfoldW<<<dim3(NB), 128, 0, stream>>>(convw, gamma, beta, wgT2, wbArr, wgsArr);

        for (int b0 = 0; b0 < BB; b0 += nbper) {
            int nb = (BB - b0 < nbper) ? (BB - b0) : nbper;
            kstat<<<dim3(63, 4, nb), 256, 0, stream>>>(sep, xt, partials, b0);
            kmm<<<dim3(8, NB, nb), 256, 0, stream>>>(xt, wgT2, partials, wbArr, wgsArr, convb, ctxr, ctxi, out, b0, outSize);
        }
    } else {
        kreal<32, 2, 0><<<dim3(11, BB), 256, 0, stream>>>(sep, ctxr, ctxi, gamma, beta, convw, convb, out, outSize);
        kreal<64, 4, 1><<<dim3(12, BB), 256, 0, stream>>>(sep, ctxr, ctxi, gamma, beta, convw, convb, out, outSize);
        kreal<128, 8, 2><<<dim3(8, BB), 256, 0, stream>>>(sep, ctxr, ctxi, gamma, beta, convw, convb, out, outSize);
    }
}

// Round 10
// 83.376 us; speedup vs baseline: 10.4516x; 1.0539x over previous
//
#include <hip/hip_runtime.h>

typedef unsigned short u16;
typedef unsigned int u32;

#define BB 8
#define CC 128
#define TT_ 1000
#define TPAD 1024
#define NB 31
#define MAXBW 16
#define MAXOC 128

typedef __bf16 bf16x8 __attribute__((ext_vector_type(8)));
typedef float f32x4 __attribute__((ext_vector_type(4)));

__device__ __forceinline__ u16 f2bf(float f) {
    u32 u = __float_as_uint(f);
    return (u16)((u + 0x7fffu + ((u >> 16) & 1u)) >> 16);
}
__device__ __forceinline__ float bf2f(u16 h) { return __uint_as_float(((u32)h) << 16); }
__device__ __forceinline__ int bandBW(int i) { return (i < 10) ? 3 : ((i < 22) ? 8 : ((i < 30) ? 16 : 3)); }
__device__ __forceinline__ int bandF0(int i) {
    return (i < 10) ? 3 * i : ((i < 22) ? 30 + 8 * (i - 10) : ((i < 30) ? 126 + 16 * (i - 22) : 254));
}

// ==================== FULL PATH ====================

// kstat v9b: r4/r6-proven streaming transpose; occupancy raised to 5 blocks/CU
// (LDS 32,000B x 5 = 160,000 <= 163,840; VGPR cap 102 fits the 16-deep pipeline).
__global__ __launch_bounds__(256, 5) void kstat(const float* __restrict__ x,
                                                u16* __restrict__ xt,
                                                float* __restrict__ partials,
                                                int b0) {
    const int tw = blockIdx.x, cg = blockIdx.y, bl = blockIdx.z, b = b0 + bl;
    const int tid = threadIdx.x, lane = tid & 63, w = tid >> 6;
    __shared__ __align__(16) u16 tile[32 * 500];   // 32,000 B
    const int NF4 = (tw == 62) ? 62 : 124;

    if (tw == 62) {                                // zero-fill pad region
        u32* t32 = (u32*)tile;
        for (int n = tid; n < 8000; n += 256) t32[n] = 0;
        __syncthreads();
    }

    const f32x4* src4 = (const f32x4*)(x + (size_t)b * (CC * TT_ * NB));
    const int fbase = tw * 124;

    // load phase: 16 float4/thread, all issued before any use
    f32x4 v[16];
    #pragma unroll
    for (int k = 0; k < 8; ++k) {
        const int c = cg * 32 + w * 8 + k;
        const f32x4* p = src4 + (size_t)c * 7750 + fbase;
        int o0 = lane, o1 = 64 + lane;
        o0 = (o0 < NF4) ? o0 : 0;
        o1 = (o1 < NF4) ? o1 : 0;
        v[2 * k]     = p[o0];
        v[2 * k + 1] = p[o1];
    }
    #pragma unroll
    for (int k = 0; k < 16; ++k) asm volatile("" : "+v"(v[k]));
    __builtin_amdgcn_sched_barrier(0);

    // convert + LDS write: one b64 per float4, lane-linear
    #pragma unroll
    for (int k = 0; k < 8; ++k) {
        u16* row = tile + (w * 8 + k) * 500;
        #pragma unroll
        for (int it = 0; it < 2; ++it) {
            const int off = it * 64 + lane;
            f32x4 vv = v[2 * k + it];
            ushort4 pk;
            pk.x = f2bf(vv.x); pk.y = f2bf(vv.y); pk.z = f2bf(vv.z); pk.w = f2bf(vv.w);
            if (off < NF4) *(ushort4*)(row + 4 * off) = pk;
        }
    }
    __syncthreads();

    // store pass: gather 8 c's per uint4, 256B runs
    uint4* dst4 = (uint4*)xt;
    const int t0 = tw * 16;
    for (int n = tid; n < 1984; n += 256) {
        int task = n >> 4, m = n & 15;
        int band = task >> 2, cbl = task & 3;
        int fidx = m * 31 + band;
        u16 e[8];
        #pragma unroll
        for (int j = 0; j < 8; ++j)
            e[j] = tile[(8 * cbl + j) * 500 + fidx];
        uint4 u;
        u.x = (u32)e[0] | ((u32)e[1] << 16);
        u.y = (u32)e[2] | ((u32)e[3] << 16);
        u.z = (u32)e[4] | ((u32)e[5] << 16);
        u.w = (u32)e[6] | ((u32)e[7] << 16);
        dst4[((size_t)(bl * NB + band) * 16 + (cg * 4 + cbl)) * TPAD + t0 + m] = u;
    }

    // stats: 8 lanes/band, shfl reduce
    if (tid < 248) {
        int band = tid >> 3, slot = tid & 7;
        float s = 0.f, sq = 0.f;
        #pragma unroll
        for (int ci = 0; ci < 32; ++ci) {
            #pragma unroll
            for (int d = 0; d < 2; ++d) {
                float f = bf2f(tile[ci * 500 + (2 * slot + d) * 31 + band]);
                s += f; sq += f * f;
            }
        }
        #pragma unroll
        for (int off = 1; off < 8; off <<= 1) {
            s  += __shfl_xor(s, off);
            sq += __shfl_xor(sq, off);
        }
        if (slot == 0) {
            int ch = tw * 4 + cg;
            *(float2*)&partials[((size_t)(b * NB + band) * 256 + ch) * 2] = make_float2(s, sq);
        }
    }
}

// kfoldW (standalone, once per run — r6-proven; fused variants regressed).
__global__ __launch_bounds__(128) void kfoldW(const float* __restrict__ w,
                                              const float* __restrict__ gamma,
                                              const float* __restrict__ beta,
                                              u16* __restrict__ wgT2,
                                              float* __restrict__ wbArr,
                                              float* __restrict__ wgsArr) {
    const int i = blockIdx.x, tid = threadIdx.x;
    __shared__ float g[CC], be[CC];
    g[tid] = gamma[i * CC + tid];
    be[tid] = beta[i * CC + tid];
    __syncthreads();
    const int oc = bandBW(i) * 8;
    float wb = 0.f, wgs = 0.f;
    for (int c = 0; c < CC; ++c) {
        float wv = w[(size_t)(i * MAXOC + tid) * CC + c];
        wb += wv * be[c];
        wgs += wv * g[c];
    }
    wbArr[i * CC + tid] = wb;
    wgsArr[i * CC + tid] = wgs;
    const float gc = g[tid];
    for (int o = 0; o < MAXOC; ++o) {
        float wv = w[(size_t)(i * MAXOC + o) * CC + tid];
        wgT2[(size_t)(i * MAXOC + o) * CC + tid] = (o < oc) ? f2bf(wv * gc) : (u16)0;
    }
}

// kmm v7b: in-register GLU epilogue (r9-verified) + ctx PREFETCH hoisted
// before the MFMA cluster (ctx loads depend only on t0 -> HBM latency hides
// under 16-64 MFMAs). Index clamped to t<1000 (avoids tail OOB on last row).
template <int ROWS, int WM, int WN, int RF, int CF, int TSTEP, int NSTEPS>
__device__ __forceinline__ void kmm_body(float* __restrict__ bo, float* __restrict__ red,
                                         const u16* __restrict__ xt,
                                         const u16* __restrict__ wgT2,
                                         const float* __restrict__ partials,
                                         const float* __restrict__ wbArr,
                                         const float* __restrict__ wgsArr,
                                         const float* __restrict__ cb,
                                         const float* __restrict__ ctxr,
                                         const float* __restrict__ ctxi,
                                         float* __restrict__ out,
                                         int i, int b, int bl, int bx, long long outSize) {
    const int tid = threadIdx.x;
    const int w = tid >> 6, l = tid & 63;
    const int wm = w % WM, wn = w / WM;
    const int RB = wm * 16 * RF;
    const int CB = wn * 16 * CF;
    const int lr = l & 15, lk = l >> 4;
    const int bw = bandBW(i), F0 = bandF0(i);

    // A fragments with GLU row permutation (overlaps the stats reduce)
    const uint4* wb4 = (const uint4*)(wgT2 + (size_t)i * MAXOC * CC);
    bf16x8 a[RF][4];
    #pragma unroll
    for (int rf = 0; rf < RF; ++rf) {
        const int rt = RB + rf * 16 + lr;
        const int lrow = (rt & 3) * 2 * bw + (rt >> 2);
        #pragma unroll
        for (int ks = 0; ks < 4; ++ks)
            a[rf][ks] = __builtin_bit_cast(bf16x8,
                wb4[(lrow * CC + lk * 8 + ks * 32) >> 3]);
    }

    // fused stats reduction
    float s = 0.f, sq = 0.f;
    for (int n = tid; n < 252; n += 256) {
        float2 p = *(const float2*)&partials[((size_t)(b * NB + i) * 256 + n) * 2];
        s += p.x; sq += p.y;
    }
    #pragma unroll
    for (int off = 1; off < 64; off <<= 1) {
        s  += __shfl_xor(s, off);
        sq += __shfl_xor(sq, off);
    }
    if ((tid & 63) == 0) {
        red[(tid >> 6) * 2]     = s;
        red[(tid >> 6) * 2 + 1] = sq;
    }
    __syncthreads();
    s  = red[0] + red[2] + red[4] + red[6];
    sq = red[1] + red[3] + red[5] + red[7];
    const float mean = s * (1.f / 128000.f);
    const float var  = sq * (1.f / 128000.f) - mean * mean;
    const float rstd = rsqrtf(var + 1e-8f);
    if (tid < ROWS)
        bo[tid] = cb[i * MAXOC + tid] + wbArr[i * CC + tid] - mean * rstd * wgsArr[i * CC + tid];
    __syncthreads();

    // per-rf quad info (bias quad, ctx/out row offsets, validity)
    bool  qv[RF];
    float bq[RF][4];
    size_t coff[RF];
    long long roff[RF];
    #pragma unroll
    for (int rf = 0; rf < RF; ++rf) {
        int q = RB / 4 + rf * 4 + lk;
        qv[rf] = (q < 2 * bw);
        int qc = qv[rf] ? q : 0;
        int ss = (qc >= bw) ? 1 : 0;
        int f  = qc - ss * bw;
        bq[rf][0] = bo[qc];
        bq[rf][1] = bo[2 * bw + qc];
        bq[rf][2] = bo[4 * bw + qc];
        bq[rf][3] = bo[6 * bw + qc];
        coff[rf] = ((size_t)(i * BB + b) * MAXBW + f) * TT_;
        roff[rf] = ((long long)((b * 2 + ss) * 257 + F0 + f)) * TT_;
    }

    const uint4* xb4 = ((const uint4*)xt) + (size_t)(bl * NB + i) * 16 * TPAD;

    for (int st = 0; st < NSTEPS; ++st) {
        const int t0 = (bx * NSTEPS + st) * TSTEP;

        // B fragments (blocked-c layout: cblk = lk + 4*ks)
        bf16x8 bf[CF][4];
        #pragma unroll
        for (int cf = 0; cf < CF; ++cf)
            #pragma unroll
            for (int ks = 0; ks < 4; ++ks)
                bf[cf][ks] = __builtin_bit_cast(bf16x8,
                    xb4[(size_t)(lk + ks * 4) * TPAD + (t0 + CB + cf * 16 + lr)]);

        // ctx prefetch: issue before MFMA cluster (latency hidden under MFMA)
        float crv[RF][CF], civ[RF][CF];
        #pragma unroll
        for (int rf = 0; rf < RF; ++rf)
            #pragma unroll
            for (int cf = 0; cf < CF; ++cf) {
                int t = t0 + CB + cf * 16 + lr;
                int tc = (t < TT_) ? t : 0;          // clamp: avoid tail OOB
                crv[rf][cf] = ctxr[coff[rf] + tc];
                civ[rf][cf] = ctxi[coff[rf] + tc];
            }

        f32x4 acc[RF][CF];
        #pragma unroll
        for (int rf = 0; rf < RF; ++rf)
            #pragma unroll
            for (int cf = 0; cf < CF; ++cf)
                acc[rf][cf] = (f32x4){0.f, 0.f, 0.f, 0.f};

        #pragma unroll
        for (int ks = 0; ks < 4; ++ks)
            #pragma unroll
            for (int rf = 0; rf < RF; ++rf)
                #pragma unroll
                for (int cf = 0; cf < CF; ++cf)
                    acc[rf][cf] = __builtin_amdgcn_mfma_f32_16x16x32_bf16(
                        a[rf][ks], bf[cf][ks], acc[rf][cf], 0, 0, 0);

        // in-register epilogue: bias+relu -> GLU -> complex mask -> store
        #pragma unroll
        for (int rf = 0; rf < RF; ++rf)
            #pragma unroll
            for (int cf = 0; cf < CF; ++cf) {
                const int t = t0 + CB + cf * 16 + lr;
                if (qv[rf] && t < TT_) {
                    float a0 = fmaxf(rstd * acc[rf][cf][0] + bq[rf][0], 0.f);
                    float a1 = fmaxf(rstd * acc[rf][cf][1] + bq[rf][1], 0.f);
                    float a2 = fmaxf(rstd * acc[rf][cf][2] + bq[rf][2], 0.f);
                    float a3 = fmaxf(rstd * acc[rf][cf][3] + bq[rf][3], 0.f);
                    float mr = a0 * (1.f / (1.f + __expf(-a2)));
                    float mi = a1 * (1.f / (1.f + __expf(-a3)));
                    long long ridx = roff[rf] + t;
                    if (ridx < outSize)
                        out[ridx] = crv[rf][cf] * mr - civ[rf][cf] * mi;
                }
            }
    }
}

__global__ __launch_bounds__(256) void kmm(const u16* __restrict__ xt,
                                           const u16* __restrict__ wgT2,
                                           const float* __restrict__ partials,
                                           const float* __restrict__ wbArr,
                                           const float* __restrict__ wgsArr,
                                           const float* __restrict__ cb,
                                           const float* __restrict__ ctxr,
                                           const float* __restrict__ ctxi,
                                           float* __restrict__ out,
                                           int b0, long long outSize) {
    __shared__ float bo[128];
    __shared__ float red[8];
    const int bx = blockIdx.x, i = blockIdx.y, bl = blockIdx.z, b = b0 + bl;
    if (i < 10 || i == 30)
        kmm_body<32, 2, 2, 1, 4, 128, 1>(bo, red, xt, wgT2, partials, wbArr, wgsArr, cb, ctxr, ctxi, out, i, b, bl, bx, outSize);
    else if (i < 22)
        kmm_body<64, 4, 1, 1, 4, 64, 2>(bo, red, xt, wgT2, partials, wbArr, wgsArr, cb, ctxr, ctxi, out, i, b, bl, bx, outSize);
    else
        kmm_body<128, 4, 1, 2, 2, 32, 4>(bo, red, xt, wgT2, partials, wbArr, wgsArr, cb, ctxr, ctxi, out, i, b, bl, bx, outSize);
}

// ==================== FALLBACK (zero workspace) ====================
template <int ROWS, int RPT, int BCLASS>
__global__ __launch_bounds__(256) void kreal(const float* __restrict__ x,
                                             const float* __restrict__ ctxr,
                                             const float* __restrict__ ctxi,
                                             const float* __restrict__ gamma,
                                             const float* __restrict__ beta,
                                             const float* __restrict__ w,
                                             const float* __restrict__ cb,
                                             float* __restrict__ out,
                                             long long outSize) {
    constexpr int TCH = 64, TPT = 4;
    const int by = blockIdx.x, b = blockIdx.y;
    const int i = (BCLASS == 0) ? (by < 10 ? by : 30) : (BCLASS == 1 ? 10 + by : 22 + by);
    const int tid = threadIdx.x, tx = tid & 15, ty = tid >> 4;

    __shared__ float XN[CC][TCH];
    __shared__ float WT[16][ROWS];
    __shared__ float gl[CC], bt[CC];
    __shared__ float red[8];

    const float* xb = x + (size_t)b * CC * TT_ * NB + i;

    if (tid < CC) { gl[tid] = gamma[i * CC + tid]; bt[tid] = beta[i * CC + tid]; }

    float s = 0.f, sq = 0.f;
    for (int n = tid; n < CC * TT_; n += 256) {
        float v = xb[(size_t)n * NB];
        s += v; sq += v * v;
    }
    #pragma unroll
    for (int off = 1; off < 64; off <<= 1) {
        s  += __shfl_xor(s, off);
        sq += __shfl_xor(sq, off);
    }
    if ((tid & 63) == 0) { red[(tid >> 6) * 2] = s; red[(tid >> 6) * 2 + 1] = sq; }
    __syncthreads();
    s  = red[0] + red[2] + red[4] + red[6];
    sq = red[1] + red[3] + red[5] + red[7];
    const float mean = s * (1.f / 128000.f);
    const float var  = sq * (1.f / 128000.f) - mean * mean;
    const float rstd = rsqrtf(var + 1e-8f);

    const int bw = bandBW(i), F0 = bandF0(i);
    const float* wband = w + (size_t)i * MAXOC * CC;

    for (int t0 = 0; t0 < TT_; t0 += TCH) {
        __syncthreads();
        for (int n = tid; n < CC * TCH; n += 256) {
            int c = n / TCH, tl = n % TCH;
            int t = t0 + tl;
            float v = (t < TT_) ? xb[((size_t)c * TT_ + t) * NB] : 0.f;
            XN[c][tl] = (v - mean) * rstd * gl[c] + bt[c];
        }

        float acc[RPT][TPT];
        #pragma unroll
        for (int r = 0; r < RPT; ++r)
            #pragma unroll
            for (int q = 0; q < TPT; ++q) acc[r][q] = 0.f;

        for (int k0 = 0; k0 < CC; k0 += 16) {
            for (int n = tid; n < 16 * ROWS; n += 256) {
                int kk = n / ROWS, o = n % ROWS;
                WT[kk][o] = wband[(size_t)o * CC + (k0 + kk)];
            }
            __syncthreads();
            #pragma unroll
            for (int kk = 0; kk < 16; ++kk) {
                float wv[RPT], xv[TPT];
                #pragma unroll
                for (int r = 0; r < RPT; ++r) wv[r] = WT[kk][ty * RPT + r];
                #pragma unroll
                for (int q = 0; q < TPT; ++q) xv[q] = XN[k0 + kk][tx * TPT + q];
                #pragma unroll
                for (int r = 0; r < RPT; ++r)
                    #pragma unroll
                    for (int q = 0; q < TPT; ++q) acc[r][q] = fmaf(wv[r], xv[q], acc[r][q]);
            }
            __syncthreads();
        }

        float* Yb = &XN[0][0];
        #pragma unroll
        for (int r = 0; r < RPT; ++r) {
            int o = ty * RPT + r;
            float bv = cb[i * MAXOC + o];
            #pragma unroll
            for (int q = 0; q < TPT; ++q)
                Yb[o * TCH + tx * TPT + q] = fmaxf(acc[r][q] + bv, 0.f);
        }
        __syncthreads();

        const int jobs = 2 * bw * TCH;
        for (int n = tid; n < jobs; n += 256) {
            int tl = n % TCH, sf = n / TCH;
            int ss = sf / bw, f = sf - ss * bw;
            int t = t0 + tl;
            if (t < TT_) {
                float lrv = Yb[(ss * bw + f) * TCH + tl];
                float liv = Yb[(2 * bw + ss * bw + f) * TCH + tl];
                float grv = Yb[(4 * bw + ss * bw + f) * TCH + tl];
                float giv = Yb[(6 * bw + ss * bw + f) * TCH + tl];
                float mr = lrv * (1.f / (1.f + __expf(-grv)));
                float mi = liv * (1.f / (1.f + __expf(-giv)));
                size_t cidx = ((size_t)(i * BB + b) * MAXBW + f) * TT_ + t;
                float cr = ctxr[cidx], ci = ctxi[cidx];
                long long ridx = ((long long)((b * 2 + ss) * 257 + F0 + f)) * TT_ + t;
                if (ridx < outSize) out[ridx] = cr * mr - ci * mi;
            }
        }
    }
}

extern "C" void kernel_launch(void* const* d_in, const int* in_sizes, int n_in,
                              void* d_out, int out_size, void* d_ws, size_t ws_size,
                              hipStream_t stream) {
    const float* sep   = (const float*)d_in[0];
    const float* ctxr  = (const float*)d_in[2];
    const float* ctxi  = (const float*)d_in[3];
    const float* gamma = (const float*)d_in[4];
    const float* beta  = (const float*)d_in[5];
    const float* convw = (const float*)d_in[6];
    const float* convb = (const float*)d_in[7];
    float* out = (float*)d_out;

    long long outSize = (long long)out_size;   // real plane, strictly guarded

    const size_t fixedEnd = 1555456;
    const size_t perB = (size_t)NB * 16 * TPAD * 16;  // 8,126,464 B per batch

    if (ws_size >= fixedEnd + perB) {
        char* ws = (char*)d_ws;
        float* partials = (float*)(ws + 0);          // 8*31*256*2*4 = 507,904 B
        float* wbArr    = (float*)(ws + 507904);     // 15,872 B
        float* wgsArr   = (float*)(ws + 523776);     // 15,872 B
        u16*   wgT2     = (u16*)(ws + 539648);       // 31*128*128*2 = 1,015,808 B
        u16*   xt       = (u16*)(ws + 1555456);

        int nbper = (int)((ws_size - fixedEnd) / perB);
        if (nbper > BB) nbper = BB;

        kfoldW<<<dim3(NB), 128, 0, stream>>>(convw, gamma, beta, wgT2, wbArr, wgsArr);

        for (int b0 = 0; b0 < BB; b0 += nbper) {
            int nb = (BB - b0 < nbper) ? (BB - b0) : nbper;
            kstat<<<dim3(63, 4, nb), 256, 0, stream>>>(sep, xt, partials, b0);
            kmm<<<dim3(8, NB, nb), 256, 0, stream>>>(xt, wgT2, partials, wbArr, wgsArr, convb, ctxr, ctxi, out, b0, outSize);
        }
    } else {
        kreal<32, 2, 0><<<dim3(11, BB), 256, 0, stream>>>(sep, ctxr, ctxi, gamma, beta, convw, convb, out, outSize);
        kreal<64, 4, 1><<<dim3(12, BB), 256, 0, stream>>>(sep, ctxr, ctxi, gamma, beta, convw, convb, out, outSize);
        kreal<128, 8, 2><<<dim3(8, BB), 256, 0, stream>>>(sep, ctxr, ctxi, gamma, beta, convw, convb, out, outSize);
    }
}